// Round 9
// baseline (121.350 us; speedup 1.0000x reference)
//
#include <hip/hip_runtime.h>
#include <hip/hip_bf16.h>

typedef __attribute__((ext_vector_type(4))) float f32x4;

constexpr int BQ  = 4096;          // batch per view
constexpr int DD  = 128;           // dim
constexpr int N2  = 2 * BQ;        // 8192
constexpr int NCHK = 16;           // column chunks (512 cols each)
constexpr int NCT  = 8;            // 64-col tiles per chunk
// exp(s/T) = exp2(s * 2/ln2); pre-scale matrix by sqrt(2.8853900817779268)
constexpr float SQS = 1.6986433f;

// ---- kernel 1: fp32 -> fp8(e4m3) in MFMA-fragment order, keys, counters ----
// obF layout: frag(group,kk) = 64 lanes x 8 bytes at index (group*4+kk)*64+lane
// (long units). Lane l: row = group*16 + (l&15), k = kk*32 + (l>>4)*8 + j.
__global__ __launch_bounds__(256) void convert_k(const float* __restrict__ a,
        const float* __restrict__ b, const int* __restrict__ tgt,
        long* __restrict__ obF, int* __restrict__ key, int* __restrict__ ctrs)
{
    int t = blockIdx.x * 256 + threadIdx.x;          // 131072 threads
    if (t < 65) ctrs[t] = 0;                         // ctr[64] + ctr2
    int row = t >> 4, c8 = t & 15;
    const float* src = (row < BQ) ? (a + (size_t)row * DD + c8 * 8)
                                  : (b + (size_t)(row - BQ) * DD + c8 * 8);
    float4 v0 = reinterpret_cast<const float4*>(src)[0];
    float4 v1 = reinterpret_cast<const float4*>(src)[1];
    int lo = __builtin_amdgcn_cvt_pk_fp8_f32(v0.x * SQS, v0.y * SQS, 0, false);
    lo     = __builtin_amdgcn_cvt_pk_fp8_f32(v0.z * SQS, v0.w * SQS, lo, true);
    int hi = __builtin_amdgcn_cvt_pk_fp8_f32(v1.x * SQS, v1.y * SQS, 0, false);
    hi     = __builtin_amdgcn_cvt_pk_fp8_f32(v1.z * SQS, v1.w * SQS, hi, true);
    long v = (((long)hi) << 32) | (unsigned)lo;
    int frag = ((row >> 4) * 4 + (c8 >> 2)) * 64 + (c8 & 3) * 16 + (row & 15);
    obF[frag] = v;

    if (t < N2) {
        // excl(i,j) == (key[i]==key[j]) covers BOTH the pair mask and the
        // target mask (rowmod==colmod implies identical target).
        int tv = tgt[t & (BQ - 1)];
        key[t] = (tv == -1) ? (0x40000000 + (t & (BQ - 1))) : tv;
    }
}

// ---- kernel 2: fused fp8 Gram + exp + mask + row sums + full loss ----------
// grid 1024 = 64 row-tiles x 16 chunks; 256 thr = 4 waves (2wr x 2wc).
// Wave tile 64 rows x 32 cols per ct. No barriers in the hot loop; B read
// straight from L2 with 2-deep ping-pong register prefetch. Loss finished
// in-kernel: per-rt last block reduces 16 chunk partials (fixed order),
// global last block reduces 64 tile sums (fixed order) -> deterministic.
__global__ __launch_bounds__(256, 3) void simloss_main(
        const long* __restrict__ F8, const int* __restrict__ key,
        float* __restrict__ pf, float* __restrict__ png,
        int* __restrict__ ctr, int* __restrict__ ctr2,
        float* __restrict__ bpart, float* __restrict__ outp)
{
    __shared__ float rred[2][128][2];    // row partials across wc
    __shared__ int winflag;

    const int tid  = threadIdx.x;
    const int lane = tid & 63;
    const int wid  = tid >> 6;
    const int wr   = wid >> 1;           // 0..1 (64-row half)
    const int wc   = wid & 1;            // 0..1 (32-col half)
    const int l15  = lane & 15;
    const int l4   = lane >> 4;

    // XCD swizzle: 1024 blocks; chunks {2x, 2x+1} stay on XCD x
    const int raw = blockIdx.x;
    const int bid = (raw & 7) * 128 + (raw >> 3);
    const int ch  = bid >> 6;            // 0..15
    const int rt  = bid & 63;            // 0..63
    const int rowbase = rt * 128;

    // A fragments: wave wr owns rows wr*64..wr*64+63 = groups rt*8+wr*4+m
    long af[4][4];
#pragma unroll
    for (int m = 0; m < 4; ++m)
#pragma unroll
        for (int kk = 0; kk < 4; ++kk)
            af[m][kk] = F8[((rt * 8 + wr * 4 + m) * 4 + kk) * 64 + lane];

    int rk[4][4];
#pragma unroll
    for (int m = 0; m < 4; ++m)
#pragma unroll
        for (int r = 0; r < 4; ++r)
            rk[m][r] = key[rowbase + wr * 64 + m * 16 + l4 * 4 + r];

    float fs[4][4] = {}, ns[4][4] = {};

    // B base: frag index = (group)*4+kk, group = ch*32 + ct*4 + wc*2 + n
    const long* Bw = F8 + (size_t)(ch * 128 + wc * 8) * 64 + lane;
    const int*  kp = key + ch * 512 + wc * 32 + l15;

    auto loadB = [&](long bx[8], int ct) {
        const long* p = Bw + ct * 1024;
#pragma unroll
        for (int q = 0; q < 8; ++q) bx[q] = p[q * 64];
    };
    auto compute = [&](const long bx[8], int ct) {
        int ck0 = kp[ct * 64];
        int ck1 = kp[ct * 64 + 16];
        f32x4 acc[4][2] = {};
#pragma unroll
        for (int kk = 0; kk < 4; ++kk)
#pragma unroll
            for (int m = 0; m < 4; ++m) {
                acc[m][0] = __builtin_amdgcn_mfma_f32_16x16x32_fp8_fp8(
                    af[m][kk], bx[kk], acc[m][0], 0, 0, 0);
                acc[m][1] = __builtin_amdgcn_mfma_f32_16x16x32_fp8_fp8(
                    af[m][kk], bx[4 + kk], acc[m][1], 0, 0, 0);
            }
#pragma unroll
        for (int m = 0; m < 4; ++m)
#pragma unroll
            for (int r = 0; r < 4; ++r) {
                float e0 = __builtin_amdgcn_exp2f(acc[m][0][r]);
                float e1 = __builtin_amdgcn_exp2f(acc[m][1][r]);
                fs[m][r] += e0 + e1;
                ns[m][r] += ((rk[m][r] == ck0) ? 0.0f : e0)
                          + ((rk[m][r] == ck1) ? 0.0f : e1);
            }
    };

    long bA[8], bB[8];
    loadB(bA, 0);
#pragma unroll 1
    for (int ct = 0; ct < NCT; ct += 2) {
        loadB(bB, ct + 1);            // prefetch next tile during compute
        compute(bA, ct);
        if (ct + 2 < NCT) loadB(bA, ct + 2);
        compute(bB, ct + 1);
    }

    // reduce across the 16 column-lanes, combine wc halves via LDS
#pragma unroll
    for (int m = 0; m < 4; ++m)
#pragma unroll
        for (int r = 0; r < 4; ++r) {
            float f = fs[m][r], g = ns[m][r];
#pragma unroll
            for (int msk = 1; msk < 16; msk <<= 1) {
                f += __shfl_xor(f, msk);
                g += __shfl_xor(g, msk);
            }
            if (l15 == 0) {
                int rl = wr * 64 + m * 16 + l4 * 4 + r;
                rred[wc][rl][0] = f;
                rred[wc][rl][1] = g;
            }
        }
    __syncthreads();
    if (tid < 128) {
        pf [ch * N2 + rowbase + tid] = rred[0][tid][0] + rred[1][tid][0];
        png[ch * N2 + rowbase + tid] = rred[0][tid][1] + rred[1][tid][1];
    }

    // ---- in-kernel finish: last block per rt does the row losses ----------
    __threadfence();
    __syncthreads();
    if (tid == 0) winflag = (atomicAdd(&ctr[rt], 1) == NCHK - 1);
    __syncthreads();
    if (!winflag) return;
    __threadfence();   // acquire: other blocks' pf/png now visible

    float li = 0.f;
    if (tid < 128) {
        int row = rowbase + tid;
        float full = 0.f, ng = 0.f;
#pragma unroll
        for (int s = 0; s < NCHK; ++s) {      // fixed order -> deterministic
            full += pf[s * N2 + row];
            ng   += png[s * N2 + row];
        }
        float o1 = full - 0.9f * ng;           // (1 - tau+) = 0.9
        float o2 = full + 818.1f * ng;         // n*tau+ - (1-tau+)
        li = (__builtin_amdgcn_logf(o2) - __builtin_amdgcn_logf(o1))
             * 0.6931471805599453f;
    }
#pragma unroll
    for (int m = 1; m < 64; m <<= 1) li += __shfl_xor(li, m);
    __shared__ float red2[2];
    if (lane == 0 && wid < 2) red2[wid] = li;
    __syncthreads();
    if (tid == 0) {
        bpart[rt] = red2[0] + red2[1];
        __threadfence();
        winflag = (atomicAdd(ctr2, 1) == 63);
    }
    __syncthreads();
    if (!winflag) return;
    __threadfence();   // acquire: all bpart visible

    if (tid < 64) {
        float v = bpart[tid];
#pragma unroll
        for (int m = 1; m < 64; m <<= 1) v += __shfl_xor(v, m);
        if (tid == 0) outp[0] = v / (float)N2;
    }
}

extern "C" void kernel_launch(void* const* d_in, const int* in_sizes, int n_in,
                              void* d_out, int out_size, void* d_ws, size_t ws_size,
                              hipStream_t stream)
{
    const float* out1 = (const float*)d_in[0];
    const float* out2 = (const float*)d_in[1];
    // d_in[2] = out_m, unused by the loss math
    const int*   tgt  = (const int*)d_in[3];
    float* out = (float*)d_out;

    // ws: obF8 1MB | pf 512KB | png 512KB | key 32KB | ctr[64]+ctr2 | bpart[64]
    long*   obF  = (long*)d_ws;
    float*  pf   = (float*)((char*)d_ws + (1u << 20));
    float*  png  = (float*)((char*)d_ws + (1u << 20) + 524288);
    int*    key  = (int*)  ((char*)d_ws + (2u << 20));
    int*    ctrs = (int*)  ((char*)d_ws + (2u << 20) + 32768);
    float*  bpart= (float*)((char*)d_ws + (2u << 20) + 32768 + 256 + 256);

    convert_k<<<512, 256, 0, stream>>>(out1, out2, tgt, obF, key, ctrs);
    simloss_main<<<1024, 256, 0, stream>>>(obF, key, pf, png,
                                           ctrs, ctrs + 64, bpart, out);
}

// Round 10
// 41.874 us; speedup vs baseline: 2.8980x; 2.8980x over previous
//
#include <hip/hip_runtime.h>
#include <hip/hip_bf16.h>

typedef __attribute__((ext_vector_type(4))) float f32x4;

constexpr int BQ  = 4096;          // batch per view
constexpr int DD  = 128;           // dim
constexpr int N2  = 2 * BQ;        // 8192
constexpr int NCHK = 8;            // column chunks (1024 cols each)
constexpr int NCT  = 16;           // 64-col tiles per chunk
// exp(s/T) = exp2(s * 2/ln2); pre-scale matrix by sqrt(2.8853900817779268)
constexpr float SQS = 1.6986433f;

// ---- kernel 1: fp32 -> fp8(e4m3) in MFMA-fragment order, keys, counters ----
// obF layout: frag(group,kk) = 64 lanes x 8 bytes at index (group*4+kk)*64+lane
// (long units). Lane l: row = group*16 + (l&15), k = kk*32 + (l>>4)*8 + j.
__global__ __launch_bounds__(256) void convert_k(const float* __restrict__ a,
        const float* __restrict__ b, const int* __restrict__ tgt,
        long* __restrict__ obF, int* __restrict__ key, int* __restrict__ ctrs)
{
    int t = blockIdx.x * 256 + threadIdx.x;          // 131072 threads
    if (t < 65) ctrs[t] = 0;                         // ctr[64] + ctr2
    int row = t >> 4, c8 = t & 15;
    const float* src = (row < BQ) ? (a + (size_t)row * DD + c8 * 8)
                                  : (b + (size_t)(row - BQ) * DD + c8 * 8);
    float4 v0 = reinterpret_cast<const float4*>(src)[0];
    float4 v1 = reinterpret_cast<const float4*>(src)[1];
    int lo = __builtin_amdgcn_cvt_pk_fp8_f32(v0.x * SQS, v0.y * SQS, 0, false);
    lo     = __builtin_amdgcn_cvt_pk_fp8_f32(v0.z * SQS, v0.w * SQS, lo, true);
    int hi = __builtin_amdgcn_cvt_pk_fp8_f32(v1.x * SQS, v1.y * SQS, 0, false);
    hi     = __builtin_amdgcn_cvt_pk_fp8_f32(v1.z * SQS, v1.w * SQS, hi, true);
    long v = (((long)hi) << 32) | (unsigned)lo;
    int frag = ((row >> 4) * 4 + (c8 >> 2)) * 64 + (c8 & 3) * 16 + (row & 15);
    obF[frag] = v;

    if (t < N2) {
        // excl(i,j) == (key[i]==key[j]) covers BOTH the pair mask and the
        // target mask (rowmod==colmod implies identical target).
        int tv = tgt[t & (BQ - 1)];
        key[t] = (tv == -1) ? (0x40000000 + (t & (BQ - 1))) : tv;
    }
}

// ---- kernel 2: fused fp8 Gram + exp + mask + row sums + fence-free finish --
// grid 512 = 64 row-tiles x 8 chunks; 256 thr = 4 waves (2wr x 2wc).
// Hot loop identical to round 8 (best): wave tile 64x32, B from L2 with
// 2-deep ping-pong register prefetch, no barriers. Finish uses AGENT-scope
// atomic stores/loads (sc-flagged, serviced at the coherent point) -- NO
// __threadfence, so no per-block L2-writeback storms. Last block per rt
// reduces that tile's 8 chunk partials in fixed slot order (deterministic);
// the 64th tile-winner does the final fixed-order 64-way sum.
__global__ __launch_bounds__(256, 3) void simloss_main(
        const long* __restrict__ F8, const int* __restrict__ key,
        float* __restrict__ pf, float* __restrict__ png,
        int* __restrict__ ctr, int* __restrict__ ctr2,
        float* __restrict__ bpart, float* __restrict__ outp)
{
    __shared__ float rred[2][128][2];    // row partials across wc
    __shared__ int winflag;
    __shared__ float red2[2];

    const int tid  = threadIdx.x;
    const int lane = tid & 63;
    const int wid  = tid >> 6;
    const int wr   = wid >> 1;           // 0..1 (64-row half)
    const int wc   = wid & 1;            // 0..1 (32-col half)
    const int l15  = lane & 15;
    const int l4   = lane >> 4;

    // XCD swizzle: 512 blocks, ch == XCD -> each XCD reads one B chunk + A
    const int raw = blockIdx.x;
    const int bid = (raw & 7) * 64 + (raw >> 3);
    const int ch  = bid >> 6;            // 0..7
    const int rt  = bid & 63;            // 0..63
    const int rowbase = rt * 128;

    // A fragments: wave wr owns rows wr*64..wr*64+63 = groups rt*8+wr*4+m
    long af[4][4];
#pragma unroll
    for (int m = 0; m < 4; ++m)
#pragma unroll
        for (int kk = 0; kk < 4; ++kk)
            af[m][kk] = F8[((rt * 8 + wr * 4 + m) * 4 + kk) * 64 + lane];

    int rk[4][4];
#pragma unroll
    for (int m = 0; m < 4; ++m)
#pragma unroll
        for (int r = 0; r < 4; ++r)
            rk[m][r] = key[rowbase + wr * 64 + m * 16 + l4 * 4 + r];

    float fs[4][4] = {}, ns[4][4] = {};

    // B base for this wave: frag index (ch*256 + ct*16 + wc*8 + n*4 + kk)*64+lane
    const long* Bw = F8 + (size_t)(ch * 256 + wc * 8) * 64 + lane;
    const int*  kp = key + ch * 1024 + wc * 32 + l15;

    auto loadB = [&](long bx[8], int ct) {
        const long* p = Bw + ct * 1024;
#pragma unroll
        for (int q = 0; q < 8; ++q) bx[q] = p[q * 64];
    };
    auto compute = [&](const long bx[8], int ct) {
        int ck0 = kp[ct * 64];
        int ck1 = kp[ct * 64 + 16];
        f32x4 acc[4][2] = {};
#pragma unroll
        for (int kk = 0; kk < 4; ++kk)
#pragma unroll
            for (int m = 0; m < 4; ++m) {
                acc[m][0] = __builtin_amdgcn_mfma_f32_16x16x32_fp8_fp8(
                    af[m][kk], bx[kk], acc[m][0], 0, 0, 0);
                acc[m][1] = __builtin_amdgcn_mfma_f32_16x16x32_fp8_fp8(
                    af[m][kk], bx[4 + kk], acc[m][1], 0, 0, 0);
            }
#pragma unroll
        for (int m = 0; m < 4; ++m)
#pragma unroll
            for (int r = 0; r < 4; ++r) {
                float e0 = __builtin_amdgcn_exp2f(acc[m][0][r]);
                float e1 = __builtin_amdgcn_exp2f(acc[m][1][r]);
                fs[m][r] += e0 + e1;
                ns[m][r] += ((rk[m][r] == ck0) ? 0.0f : e0)
                          + ((rk[m][r] == ck1) ? 0.0f : e1);
            }
    };

    long bA[8], bB[8];
    loadB(bA, 0);
#pragma unroll 1
    for (int ct = 0; ct < NCT; ct += 2) {
        loadB(bB, ct + 1);            // prefetch next tile during compute
        compute(bA, ct);
        if (ct + 2 < NCT) loadB(bA, ct + 2);
        compute(bB, ct + 1);
    }

    // reduce across the 16 column-lanes, combine wc halves via LDS
#pragma unroll
    for (int m = 0; m < 4; ++m)
#pragma unroll
        for (int r = 0; r < 4; ++r) {
            float f = fs[m][r], g = ns[m][r];
#pragma unroll
            for (int msk = 1; msk < 16; msk <<= 1) {
                f += __shfl_xor(f, msk);
                g += __shfl_xor(g, msk);
            }
            if (l15 == 0) {
                int rl = wr * 64 + m * 16 + l4 * 4 + r;
                rred[wc][rl][0] = f;
                rred[wc][rl][1] = g;
            }
        }
    __syncthreads();
    if (tid < 128) {
        // device-visible partial stores (sc-flagged; retire at waitcnt ->
        // visible at coherence point; no L2-writeback fence needed)
        __hip_atomic_store(&pf[ch * N2 + rowbase + tid],
                           rred[0][tid][0] + rred[1][tid][0],
                           __ATOMIC_RELAXED, __HIP_MEMORY_SCOPE_AGENT);
        __hip_atomic_store(&png[ch * N2 + rowbase + tid],
                           rred[0][tid][1] + rred[1][tid][1],
                           __ATOMIC_RELAXED, __HIP_MEMORY_SCOPE_AGENT);
    }
    __syncthreads();   // every wave drains vmcnt before barrier -> stores visible

    if (tid == 0) {
        int old = __hip_atomic_fetch_add(&ctr[rt], 1,
                      __ATOMIC_ACQ_REL, __HIP_MEMORY_SCOPE_AGENT);
        winflag = (old == NCHK - 1);
    }
    __syncthreads();
    if (!winflag) return;

    // ---- rt winner: row losses for this tile (fixed slot order) -----------
    float li = 0.f;
    if (tid < 128) {
        int row = rowbase + tid;
        float full = 0.f, ng = 0.f;
#pragma unroll
        for (int s = 0; s < NCHK; ++s) {
            full += __hip_atomic_load(&pf[s * N2 + row],
                        __ATOMIC_RELAXED, __HIP_MEMORY_SCOPE_AGENT);
            ng   += __hip_atomic_load(&png[s * N2 + row],
                        __ATOMIC_RELAXED, __HIP_MEMORY_SCOPE_AGENT);
        }
        float o1 = full - 0.9f * ng;           // (1 - tau+) = 0.9
        float o2 = full + 818.1f * ng;         // n*tau+ - (1-tau+)
        li = (__builtin_amdgcn_logf(o2) - __builtin_amdgcn_logf(o1))
             * 0.6931471805599453f;
    }
#pragma unroll
    for (int m = 1; m < 64; m <<= 1) li += __shfl_xor(li, m);
    if (lane == 0 && wid < 2) red2[wid] = li;
    __syncthreads();
    if (tid == 0) {
        __hip_atomic_store(&bpart[rt], red2[0] + red2[1],
                           __ATOMIC_RELAXED, __HIP_MEMORY_SCOPE_AGENT);
        int old2 = __hip_atomic_fetch_add(ctr2, 1,
                       __ATOMIC_ACQ_REL, __HIP_MEMORY_SCOPE_AGENT);
        winflag = (old2 == 63);
    }
    __syncthreads();
    if (!winflag) return;

    // ---- global winner: fixed-order 64-way sum -> mean ---------------------
    if (wid == 0) {
        float v = __hip_atomic_load(&bpart[lane],
                      __ATOMIC_RELAXED, __HIP_MEMORY_SCOPE_AGENT);
#pragma unroll
        for (int m = 1; m < 64; m <<= 1) v += __shfl_xor(v, m);
        if (lane == 0) outp[0] = v / (float)N2;
    }
}

extern "C" void kernel_launch(void* const* d_in, const int* in_sizes, int n_in,
                              void* d_out, int out_size, void* d_ws, size_t ws_size,
                              hipStream_t stream)
{
    const float* out1 = (const float*)d_in[0];
    const float* out2 = (const float*)d_in[1];
    // d_in[2] = out_m, unused by the loss math
    const int*   tgt  = (const int*)d_in[3];
    float* out = (float*)d_out;

    // ws: obF8 1MB | pf 256KB | png 256KB | key 32KB | ctr[64]+ctr2 | bpart[64]
    long*   obF  = (long*)d_ws;
    float*  pf   = (float*)((char*)d_ws + (1u << 20));
    float*  png  = (float*)((char*)d_ws + (1u << 20) + 262144);
    int*    key  = (int*)  ((char*)d_ws + (1u << 20) + 524288);
    int*    ctrs = (int*)  ((char*)d_ws + (1u << 20) + 524288 + 32768);
    float*  bpart= (float*)((char*)d_ws + (1u << 20) + 524288 + 32768 + 512);

    convert_k<<<512, 256, 0, stream>>>(out1, out2, tgt, obF, key, ctrs);
    simloss_main<<<512, 256, 0, stream>>>(obF, key, pf, png,
                                          ctrs, ctrs + 64, bpart, out);
}